// Round 5
// baseline (703.110 us; speedup 1.0000x reference)
//
#include <hip/hip_runtime.h>
#include <math.h>

#define N_NODES_C 16384
#define N_EDGES_C 196608

typedef short bf16x8 __attribute__((ext_vector_type(8)));
typedef float f32x4 __attribute__((ext_vector_type(4)));
typedef float f32x8 __attribute__((ext_vector_type(8)));

__device__ __forceinline__ float silu_f(float x) {
  return x * __builtin_amdgcn_rcpf(1.0f + __expf(-x));
}

// ---------------- CSR build ----------------
__global__ void k_count(const int* __restrict__ rcv, int* __restrict__ counts) {
  int e = blockIdx.x * 256 + threadIdx.x;
  atomicAdd(&counts[rcv[e]], 1);
}

__global__ __launch_bounds__(1024) void k_scan(const int* __restrict__ counts,
                                               int* __restrict__ row_start,
                                               int* __restrict__ cursor) {
  __shared__ int sums[1024];
  const int tid = threadIdx.x;
  int loc[16];
  int s = 0;
#pragma unroll
  for (int i = 0; i < 16; ++i) { loc[i] = counts[tid * 16 + i]; s += loc[i]; }
  sums[tid] = s;
  __syncthreads();
  for (int off = 1; off < 1024; off <<= 1) {
    int t = (tid >= off) ? sums[tid - off] : 0;
    __syncthreads();
    sums[tid] += t;
    __syncthreads();
  }
  int excl = sums[tid] - s;
#pragma unroll
  for (int i = 0; i < 16; ++i) {
    row_start[tid * 16 + i] = excl;
    cursor[tid * 16 + i] = excl;
    excl += loc[i];
  }
  if (tid == 1023) row_start[N_NODES_C] = excl;
}

__global__ void k_fill(const int* __restrict__ rcv, const int* __restrict__ snd,
                       int* __restrict__ cursor, int* __restrict__ elist,
                       int* __restrict__ snd_csr) {
  int e = blockIdx.x * 256 + threadIdx.x;
  int slot = atomicAdd(&cursor[rcv[e]], 1);
  elist[slot] = e;
  snd_csr[slot] = snd[e];
}

// ---------------- node element id + embedding ----------------
__global__ void k_elem(const float* __restrict__ attrs, int* __restrict__ elem) {
  int n = blockIdx.x * 256 + threadIdx.x;
  const float* a = attrs + n * 8;
  int best = 0;
  float bv = a[0];
#pragma unroll
  for (int z = 1; z < 8; ++z) {
    if (a[z] > bv) { bv = a[z]; best = z; }
  }
  elem[n] = best;
}

__global__ void k_embed(const float* __restrict__ attrs, const float* __restrict__ Wemb,
                        float* __restrict__ scal0, float* __restrict__ nf) {
  int gid = blockIdx.x * 256 + threadIdx.x;  // N*32 threads
  int n = gid >> 5, c = gid & 31;
  float s = 0.f;
#pragma unroll
  for (int z = 0; z < 8; ++z) s = fmaf(attrs[n * 8 + z], Wemb[z * 32 + c], s);
  scal0[gid] = s;
  float* row = nf + (size_t)n * 512 + c * 16;
  *(float4*)&row[0] = make_float4(s, 0.f, 0.f, 0.f);
  *(float4*)&row[4] = make_float4(0.f, 0.f, 0.f, 0.f);
  *(float4*)&row[8] = make_float4(0.f, 0.f, 0.f, 0.f);
  *(float4*)&row[12] = make_float4(0.f, 0.f, 0.f, 0.f);
}

// ---------------- per-edge radial MLP in CSR order (+SH on layer 0) -------
// Wave = 32 CSR positions. Lane = output neuron (weights in VGPRs);
// geometry lane-parallel (lanes 0-31). h3[p] = [hi k0..63 | lo k0..63].
__global__ __launch_bounds__(256, 3) void k_radial(
    const float* __restrict__ pos, const float* __restrict__ shifts,
    const int* __restrict__ snd, const int* __restrict__ rcv,
    const int* __restrict__ elist,
    const float* __restrict__ W1g, const float* __restrict__ W2g,
    const float* __restrict__ W3g, unsigned short* __restrict__ h3,
    float* __restrict__ Yout, const int writeY) {
  __shared__ __align__(16) float efs[4][32][8];
  __shared__ __align__(16) float hbs[4][64];
  const int wid = threadIdx.x >> 6, lane = threadIdx.x & 63;
  float w1c[8], w2c[64], w3c[64];
#pragma unroll
  for (int k = 0; k < 8; ++k) w1c[k] = W1g[k * 64 + lane];
#pragma unroll
  for (int k = 0; k < 64; ++k) w2c[k] = W2g[k * 64 + lane];
#pragma unroll
  for (int k = 0; k < 64; ++k) w3c[k] = W3g[k * 64 + lane];

  const int base = (blockIdx.x * 4 + wid) * 32;

  if (lane < 32) {
    const int p = base + lane;
    const int e = elist[p];
    const int sn = snd[e], rc = rcv[e];
    const float vx = pos[rc * 3 + 0] - pos[sn * 3 + 0] + shifts[e * 3 + 0];
    const float vy = pos[rc * 3 + 1] - pos[sn * 3 + 1] + shifts[e * 3 + 1];
    const float vz = pos[rc * 3 + 2] - pos[sn * 3 + 2] + shifts[e * 3 + 2];
    const float len = __builtin_amdgcn_sqrtf(vx * vx + vy * vy + vz * vz + 1e-18f);
    const float u = len * 0.2f;  // / R_MAX
    float fc = 0.f;
    if (u < 1.0f) {
      const float u2 = u * u, u5 = u2 * u2 * u;
      fc = 1.0f - 21.0f * u5 + 35.0f * u5 * u - 15.0f * u5 * u2;
    }
    const float pref = 0.6324555320336759f * fc * __builtin_amdgcn_rcpf(fmaxf(len, 1e-9f));
    float efv[8];
#pragma unroll
    for (int k = 0; k < 8; ++k) {
      const float pin = 3.14159274f * (float)(k + 1);
      efv[k] = pref * __sinf(pin * u);
    }
    *(float4*)&efs[wid][lane][0] = make_float4(efv[0], efv[1], efv[2], efv[3]);
    *(float4*)&efs[wid][lane][4] = make_float4(efv[4], efv[5], efv[6], efv[7]);

    if (writeY) {
      const float il = __builtin_amdgcn_rcpf(len);
      const float x = vx * il, y = vy * il, z = vz * il;
      const float x2 = x * x, y2 = y * y, z2 = z * z;
      const float s3 = 1.7320508075688772f;
      const float s15 = 3.872983346207417f;
      const float s5h = 1.118033988749895f;
      const float s35_8 = 2.091650066335189f;
      const float s105 = 10.246950765959598f;
      const float s21_8 = 1.6201851746019651f;
      const float s7h = 1.3228756555322954f;
      const float s105h = 5.123475382979799f;
      float* yp = Yout + (size_t)p * 16;
      *(float4*)&yp[0] = make_float4(1.f, s3 * x, s3 * y, s3 * z);
      *(float4*)&yp[4] = make_float4(s15 * x * y, s15 * y * z, s5h * (3.f * z2 - 1.f), s15 * x * z);
      *(float4*)&yp[8] = make_float4(0.5f * s15 * (x2 - y2), s35_8 * y * (3.f * x2 - y2),
                                     s105 * x * y * z, s21_8 * y * (5.f * z2 - 1.f));
      *(float4*)&yp[12] = make_float4(s7h * z * (5.f * z2 - 3.f), s21_8 * x * (5.f * z2 - 1.f),
                                      s105h * z * (x2 - y2), s35_8 * x * (x2 - 3.f * y2));
    }
  }

  for (int t = 0; t < 32; ++t) {
    const float4 ef0 = *(const float4*)&efs[wid][t][0];
    const float4 ef1 = *(const float4*)&efs[wid][t][4];
    float a1 = ef0.x * w1c[0];
    a1 = fmaf(ef0.y, w1c[1], a1);
    a1 = fmaf(ef0.z, w1c[2], a1);
    a1 = fmaf(ef0.w, w1c[3], a1);
    a1 = fmaf(ef1.x, w1c[4], a1);
    a1 = fmaf(ef1.y, w1c[5], a1);
    a1 = fmaf(ef1.z, w1c[6], a1);
    a1 = fmaf(ef1.w, w1c[7], a1);
    hbs[wid][lane] = silu_f(a1);
    float p0 = 0.f, p1 = 0.f, p2 = 0.f, p3 = 0.f;
#pragma unroll
    for (int k4 = 0; k4 < 16; ++k4) {
      const float4 hb = *(const float4*)&hbs[wid][k4 * 4];
      p0 = fmaf(hb.x, w2c[k4 * 4 + 0], p0);
      p1 = fmaf(hb.y, w2c[k4 * 4 + 1], p1);
      p2 = fmaf(hb.z, w2c[k4 * 4 + 2], p2);
      p3 = fmaf(hb.w, w2c[k4 * 4 + 3], p3);
    }
    hbs[wid][lane] = silu_f((p0 + p1) + (p2 + p3));
    p0 = p1 = p2 = p3 = 0.f;
#pragma unroll
    for (int k4 = 0; k4 < 16; ++k4) {
      const float4 hb = *(const float4*)&hbs[wid][k4 * 4];
      p0 = fmaf(hb.x, w3c[k4 * 4 + 0], p0);
      p1 = fmaf(hb.y, w3c[k4 * 4 + 1], p1);
      p2 = fmaf(hb.z, w3c[k4 * 4 + 2], p2);
      p3 = fmaf(hb.w, w3c[k4 * 4 + 3], p3);
    }
    const float hv = silu_f((p0 + p1) + (p2 + p3));
    const unsigned hb16 = __float_as_uint(hv) & 0xFFFF0000u;
    const float lof = hv - __uint_as_float(hb16);
    h3[(size_t)(base + t) * 128 + lane] = (unsigned short)(hb16 >> 16);
    h3[(size_t)(base + t) * 128 + 64 + lane] = (unsigned short)(__float_as_uint(lof) >> 16);
  }
}

// ---------------- node-gathered W4 GEMM via MFMA, sequential streams ------
// kh = K-half (disjoint h3 bytes); kh-pair blocks are 8 apart in blockIdx so
// both land on the same XCD (round-robin) and share Y/scal in L2.
// Block = 4 waves = 4 column quarters walking 16 contiguous nodes.
// B-tiles (hi/lo bf16) live in VGPRs; s read per-lane from L2-resident scal
// via snd_csr (no sedge stream, no sv-bpermutes). C/D: col=lm, row=grp*4+reg.
__global__ __launch_bounds__(256, 4) void k_gather(
    const unsigned short* __restrict__ h3, const float* __restrict__ W4g,
    const float* __restrict__ Yb, const float* __restrict__ scal,
    const int* __restrict__ snd_csr, const int* __restrict__ row_start,
    float* __restrict__ aggh) {
  const int kh = (blockIdx.x >> 3) & 1;
  const int ng = ((blockIdx.x >> 4) << 3) | (blockIdx.x & 7);
  const int w = threadIdx.x >> 6, lane = threadIdx.x & 63;
  const int grp = lane >> 4, lm = lane & 15;

  // B fragments: 8 tiles (cols w*128 + t*16 + lm), K-half kh, hi/lo planes.
  bf16x8 bhi[8], blo[8];
#pragma unroll
  for (int t = 0; t < 8; ++t) {
    const int col = w * 128 + t * 16 + lm;
#pragma unroll
    for (int j = 0; j < 8; ++j) {
      const float wv = W4g[(kh * 32 + grp * 8 + j) * 512 + col];
      const unsigned hb = __float_as_uint(wv) & 0xFFFF0000u;
      bhi[t][j] = (short)(hb >> 16);
      blo[t][j] = (short)(__float_as_uint(wv - __uint_as_float(hb)) >> 16);
    }
  }

  float* agg = aggh + (size_t)kh * N_NODES_C * 512;
  const int nBeg = ng * 16;
  for (int n = nBeg; n < nBeg + 16; ++n) {
    const int e0 = row_start[n], e1 = row_start[n + 1];
    float outv[8] = {0.f, 0.f, 0.f, 0.f, 0.f, 0.f, 0.f, 0.f};
    for (int p0 = e0; p0 < e1; p0 += 16) {
      bf16x8 ahi = {0, 0, 0, 0, 0, 0, 0, 0}, alo = ahi;
      const int pa = p0 + lm;
      if (pa < e1) {
        ahi = *(const bf16x8*)(h3 + (size_t)pa * 128 + kh * 32 + grp * 8);
        alo = *(const bf16x8*)(h3 + (size_t)pa * 128 + 64 + kh * 32 + grp * 8);
      }
      float Yv[4];
      f32x8 sv[4];
#pragma unroll
      for (int r = 0; r < 4; ++r) {
        const int pr = p0 + grp * 4 + r;
        Yv[r] = Yb[(size_t)pr * 16 + lm];
        const int prc = pr < N_EDGES_C ? pr : N_EDGES_C - 1;
        sv[r] = *(const f32x8*)(scal + (size_t)snd_csr[prc] * 32 + w * 8);
      }
#pragma unroll
      for (int t = 0; t < 8; ++t) {
        f32x4 acc = {0.f, 0.f, 0.f, 0.f};
        acc = __builtin_amdgcn_mfma_f32_16x16x32_bf16(ahi, bhi[t], acc, 0, 0, 0);
        acc = __builtin_amdgcn_mfma_f32_16x16x32_bf16(alo, bhi[t], acc, 0, 0, 0);
        acc = __builtin_amdgcn_mfma_f32_16x16x32_bf16(ahi, blo[t], acc, 0, 0, 0);
        float c = acc[0] * Yv[0] * sv[0][t];
        c = fmaf(acc[1] * Yv[1], sv[1][t], c);
        c = fmaf(acc[2] * Yv[2], sv[2][t], c);
        c = fmaf(acc[3] * Yv[3], sv[3][t], c);
        c += __shfl_xor(c, 16);
        c += __shfl_xor(c, 32);
        outv[t] += c;
      }
    }
    const float inv12 = 1.0f / 12.0f;
#pragma unroll
    for (int t = 0; t < 8; ++t)
      if (grp == (t >> 1))
        agg[(size_t)n * 512 + (w * 8 + t) * 16 + lm] = outv[t] * inv12;
  }
}

// ---------------- per-node: Wlin, quadratic, Wprod + skip, desc out -------
__global__ __launch_bounds__(256) void k_node(
    const float* __restrict__ aggA, const float* __restrict__ aggB,
    float* __restrict__ nf, const float* __restrict__ Wlin,
    const float* __restrict__ Wprod, const float* __restrict__ Wskip,
    const float* __restrict__ w2v, const float* __restrict__ w3v,
    const int* __restrict__ elem, float* __restrict__ scal_out,
    float* __restrict__ dout, const int layer) {
  __shared__ __align__(16) float aggs[8][512];
  __shared__ __align__(16) float nfs[8][512];
  __shared__ float bs[8][544];  // pitch 17 per channel row
  const int tid = threadIdx.x;
  const int n0 = blockIdx.x * 8;
  for (int i = tid; i < 1024; i += 256) {
    const int nl = i >> 7, qq = i & 127;
    const f32x4 va = ((const f32x4*)aggA)[(size_t)(n0 + nl) * 128 + qq];
    const f32x4 vb = ((const f32x4*)aggB)[(size_t)(n0 + nl) * 128 + qq];
    ((f32x4*)aggs)[i] = va + vb;
    ((f32x4*)nfs)[i] = ((const f32x4*)nf)[(size_t)(n0 + nl) * 128 + qq];
  }
  __syncthreads();
  const int nl = tid >> 5, o = tid & 31;
  const int n = n0 + nl;
  constexpr int SLa[4] = {0, 1, 4, 9};
  constexpr int ELa[4] = {1, 4, 9, 16};
  float a[16];
#pragma unroll
  for (int m = 0; m < 16; ++m) a[m] = 0.f;
#pragma unroll
  for (int l = 0; l < 4; ++l) {
    for (int c = 0; c < 32; ++c) {
      const float w = Wlin[(l * 32 + c) * 32 + o];
#pragma unroll
      for (int m = SLa[l]; m < ELa[l]; ++m) a[m] = fmaf(aggs[nl][c * 16 + m], w, a[m]);
    }
  }
  const float inv = a[0];
  float p2 = 0.f;
#pragma unroll
  for (int m = 0; m < 16; ++m) p2 = fmaf(a[m], a[m], p2);
  a[0] = inv + w2v[o] * p2 + w3v[o] * inv * p2;
#pragma unroll
  for (int m = 0; m < 16; ++m) bs[nl][o * 17 + m] = a[m];
  __syncthreads();
  float outv[16];
#pragma unroll
  for (int m = 0; m < 16; ++m) outv[m] = 0.f;
#pragma unroll
  for (int l = 0; l < 4; ++l) {
    for (int c = 0; c < 32; ++c) {
      const float w = Wprod[(l * 32 + c) * 32 + o];
#pragma unroll
      for (int m = SLa[l]; m < ELa[l]; ++m) outv[m] = fmaf(bs[nl][c * 17 + m], w, outv[m]);
    }
  }
  const int z = elem[n];
  const float* wsk = Wskip + z * 1024;
  for (int c = 0; c < 32; ++c) {
    const float w = wsk[c * 32 + o];
#pragma unroll
    for (int m = 0; m < 16; ++m) outv[m] = fmaf(nfs[nl][c * 16 + m], w, outv[m]);
  }
  float* op = nf + (size_t)n * 512 + o * 16;
  *(float4*)&op[0] = make_float4(outv[0], outv[1], outv[2], outv[3]);
  *(float4*)&op[4] = make_float4(outv[4], outv[5], outv[6], outv[7]);
  *(float4*)&op[8] = make_float4(outv[8], outv[9], outv[10], outv[11]);
  *(float4*)&op[12] = make_float4(outv[12], outv[13], outv[14], outv[15]);
  scal_out[n * 32 + o] = outv[0];
  dout[(size_t)n * 64 + layer * 32 + o] = outv[0];
}

extern "C" void kernel_launch(void* const* d_in, const int* in_sizes, int n_in,
                              void* d_out, int out_size, void* d_ws, size_t ws_size,
                              hipStream_t stream) {
  const float* pos = (const float*)d_in[0];
  const float* attrs = (const float*)d_in[1];
  const float* shifts = (const float*)d_in[2];
  const int* eidx = (const int*)d_in[3];
  const float* W_embed = (const float*)d_in[4];
  const float* W1 = (const float*)d_in[5];
  const float* W2 = (const float*)d_in[6];
  const float* W3 = (const float*)d_in[7];
  const float* W4 = (const float*)d_in[8];
  const float* Wlin = (const float*)d_in[9];
  const float* Wskip = (const float*)d_in[10];
  const float* w2v = (const float*)d_in[11];
  const float* w3v = (const float*)d_in[12];
  const float* Wprod = (const float*)d_in[13];
  float* out = (float*)d_out;
  const int* snd = eidx;
  const int* rcv = eidx + N_EDGES_C;

  char* p = (char*)d_ws;
  auto take = [&](size_t bytes) {
    char* q = p;
    p += (bytes + 255) & ~(size_t)255;
    return q;
  };
  int* counts = (int*)take((size_t)N_NODES_C * 4);
  int* row_start = (int*)take((size_t)(N_NODES_C + 1) * 4);
  int* cursor = (int*)take((size_t)N_NODES_C * 4);
  int* elist = (int*)take((size_t)N_EDGES_C * 4);
  int* snd_csr = (int*)take((size_t)(N_EDGES_C + 16) * 4);
  int* elem = (int*)take((size_t)N_NODES_C * 4);
  float* Ybuf = (float*)take((size_t)(N_EDGES_C + 16) * 16 * 4);
  unsigned short* h3 = (unsigned short*)take((size_t)(N_EDGES_C + 16) * 128 * 2);
  float* aggh = (float*)take((size_t)2 * N_NODES_C * 512 * 4);
  float* nf = (float*)take((size_t)N_NODES_C * 512 * 4);
  float* scal0 = (float*)take((size_t)N_NODES_C * 32 * 4);
  float* scal1 = (float*)take((size_t)N_NODES_C * 32 * 4);
  (void)ws_size; (void)in_sizes; (void)n_in; (void)out_size;

  hipMemsetAsync(counts, 0, (size_t)N_NODES_C * 4, stream);
  k_count<<<N_EDGES_C / 256, 256, 0, stream>>>(rcv, counts);
  k_scan<<<1, 1024, 0, stream>>>(counts, row_start, cursor);
  k_fill<<<N_EDGES_C / 256, 256, 0, stream>>>(rcv, snd, cursor, elist, snd_csr);
  k_elem<<<N_NODES_C / 256, 256, 0, stream>>>(attrs, elem);
  k_embed<<<N_NODES_C * 32 / 256, 256, 0, stream>>>(attrs, W_embed, scal0, nf);

  for (int i = 0; i < 2; ++i) {
    k_radial<<<1536, 256, 0, stream>>>(pos, shifts, snd, rcv, elist,
                                       W1 + (size_t)i * 8 * 64, W2 + (size_t)i * 64 * 64,
                                       W3 + (size_t)i * 64 * 64, h3, Ybuf,
                                       i == 0 ? 1 : 0);
    k_gather<<<2048, 256, 0, stream>>>(h3, W4 + (size_t)i * 64 * 512, Ybuf,
                                       i == 0 ? scal0 : scal1, snd_csr, row_start, aggh);
    k_node<<<N_NODES_C / 8, 256, 0, stream>>>(aggh, aggh + (size_t)N_NODES_C * 512, nf,
                                              Wlin + (size_t)i * 4096,
                                              Wprod + (size_t)i * 4096,
                                              Wskip + (size_t)i * 8192,
                                              w2v + (size_t)i * 32, w3v + (size_t)i * 32,
                                              elem, scal1, out, i);
  }
}

// Round 6
// 512.563 us; speedup vs baseline: 1.3718x; 1.3718x over previous
//
#include <hip/hip_runtime.h>
#include <math.h>

#define N_NODES_C 16384
#define N_EDGES_C 196608

typedef short bf16x8 __attribute__((ext_vector_type(8)));
typedef float f32x4 __attribute__((ext_vector_type(4)));
typedef float f32x8 __attribute__((ext_vector_type(8)));

__device__ __forceinline__ float silu_f(float x) {
  return x * __builtin_amdgcn_rcpf(1.0f + __expf(-x));
}

// ---------------- CSR build ----------------
__global__ void k_count(const int* __restrict__ rcv, int* __restrict__ counts) {
  int e = blockIdx.x * 256 + threadIdx.x;
  atomicAdd(&counts[rcv[e]], 1);
}

__global__ __launch_bounds__(1024) void k_scan(const int* __restrict__ counts,
                                               int* __restrict__ row_start,
                                               int* __restrict__ cursor) {
  __shared__ int sums[1024];
  const int tid = threadIdx.x;
  int loc[16];
  int s = 0;
#pragma unroll
  for (int i = 0; i < 16; ++i) { loc[i] = counts[tid * 16 + i]; s += loc[i]; }
  sums[tid] = s;
  __syncthreads();
  for (int off = 1; off < 1024; off <<= 1) {
    int t = (tid >= off) ? sums[tid - off] : 0;
    __syncthreads();
    sums[tid] += t;
    __syncthreads();
  }
  int excl = sums[tid] - s;
#pragma unroll
  for (int i = 0; i < 16; ++i) {
    row_start[tid * 16 + i] = excl;
    cursor[tid * 16 + i] = excl;
    excl += loc[i];
  }
  if (tid == 1023) row_start[N_NODES_C] = excl;
}

__global__ void k_fill(const int* __restrict__ rcv, int* __restrict__ cursor,
                       int* __restrict__ elist) {
  int e = blockIdx.x * 256 + threadIdx.x;
  int slot = atomicAdd(&cursor[rcv[e]], 1);
  elist[slot] = e;
}

// ---------------- node element id + embedding ----------------
__global__ void k_elem(const float* __restrict__ attrs, int* __restrict__ elem) {
  int n = blockIdx.x * 256 + threadIdx.x;
  const float* a = attrs + n * 8;
  int best = 0;
  float bv = a[0];
#pragma unroll
  for (int z = 1; z < 8; ++z) {
    if (a[z] > bv) { bv = a[z]; best = z; }
  }
  elem[n] = best;
}

__global__ void k_embed(const float* __restrict__ attrs, const float* __restrict__ Wemb,
                        float* __restrict__ scal0, float* __restrict__ nf) {
  int gid = blockIdx.x * 256 + threadIdx.x;  // N*32 threads
  int n = gid >> 5, c = gid & 31;
  float s = 0.f;
#pragma unroll
  for (int z = 0; z < 8; ++z) s = fmaf(attrs[n * 8 + z], Wemb[z * 32 + c], s);
  scal0[gid] = s;
  float* row = nf + (size_t)n * 512 + c * 16;
  *(float4*)&row[0] = make_float4(s, 0.f, 0.f, 0.f);
  *(float4*)&row[4] = make_float4(0.f, 0.f, 0.f, 0.f);
  *(float4*)&row[8] = make_float4(0.f, 0.f, 0.f, 0.f);
  *(float4*)&row[12] = make_float4(0.f, 0.f, 0.f, 0.f);
}

// ---------------- per-edge radial MLP in CSR order (+SH, +s-edge) ---------
// Wave = 32 CSR positions. Lane = output neuron (weights in VGPRs);
// geometry lane-parallel. h3[p] = [hi k0..63 | lo k0..63] bf16 planes.
// sedge[p][32] = scal[snd[e_p]][:]  (the R4-proven coalesced stream).
__global__ __launch_bounds__(256, 3) void k_radial(
    const float* __restrict__ pos, const float* __restrict__ shifts,
    const int* __restrict__ snd, const int* __restrict__ rcv,
    const int* __restrict__ elist, const float* __restrict__ scal,
    const float* __restrict__ W1g, const float* __restrict__ W2g,
    const float* __restrict__ W3g, unsigned short* __restrict__ h3,
    float* __restrict__ sedge, float* __restrict__ Yout, const int writeY) {
  __shared__ __align__(16) float efs[4][32][8];
  __shared__ __align__(16) float hbs[4][64];
  const int wid = threadIdx.x >> 6, lane = threadIdx.x & 63;
  float w1c[8], w2c[64], w3c[64];
#pragma unroll
  for (int k = 0; k < 8; ++k) w1c[k] = W1g[k * 64 + lane];
#pragma unroll
  for (int k = 0; k < 64; ++k) w2c[k] = W2g[k * 64 + lane];
#pragma unroll
  for (int k = 0; k < 64; ++k) w3c[k] = W3g[k * 64 + lane];

  const int base = (blockIdx.x * 4 + wid) * 32;

  if (lane < 32) {
    const int p = base + lane;
    const int e = elist[p];
    const int sn = snd[e], rc = rcv[e];
    const float vx = pos[rc * 3 + 0] - pos[sn * 3 + 0] + shifts[e * 3 + 0];
    const float vy = pos[rc * 3 + 1] - pos[sn * 3 + 1] + shifts[e * 3 + 1];
    const float vz = pos[rc * 3 + 2] - pos[sn * 3 + 2] + shifts[e * 3 + 2];
    const float len = __builtin_amdgcn_sqrtf(vx * vx + vy * vy + vz * vz + 1e-18f);
    const float u = len * 0.2f;  // / R_MAX
    float fc = 0.f;
    if (u < 1.0f) {
      const float u2 = u * u, u5 = u2 * u2 * u;
      fc = 1.0f - 21.0f * u5 + 35.0f * u5 * u - 15.0f * u5 * u2;
    }
    const float pref = 0.6324555320336759f * fc * __builtin_amdgcn_rcpf(fmaxf(len, 1e-9f));
    float efv[8];
#pragma unroll
    for (int k = 0; k < 8; ++k) {
      const float pin = 3.14159274f * (float)(k + 1);
      efv[k] = pref * __sinf(pin * u);
    }
    *(float4*)&efs[wid][lane][0] = make_float4(efv[0], efv[1], efv[2], efv[3]);
    *(float4*)&efs[wid][lane][4] = make_float4(efv[4], efv[5], efv[6], efv[7]);

    if (writeY) {
      const float il = __builtin_amdgcn_rcpf(len);
      const float x = vx * il, y = vy * il, z = vz * il;
      const float x2 = x * x, y2 = y * y, z2 = z * z;
      const float s3 = 1.7320508075688772f;
      const float s15 = 3.872983346207417f;
      const float s5h = 1.118033988749895f;
      const float s35_8 = 2.091650066335189f;
      const float s105 = 10.246950765959598f;
      const float s21_8 = 1.6201851746019651f;
      const float s7h = 1.3228756555322954f;
      const float s105h = 5.123475382979799f;
      float* yp = Yout + (size_t)p * 16;
      *(float4*)&yp[0] = make_float4(1.f, s3 * x, s3 * y, s3 * z);
      *(float4*)&yp[4] = make_float4(s15 * x * y, s15 * y * z, s5h * (3.f * z2 - 1.f), s15 * x * z);
      *(float4*)&yp[8] = make_float4(0.5f * s15 * (x2 - y2), s35_8 * y * (3.f * x2 - y2),
                                     s105 * x * y * z, s21_8 * y * (5.f * z2 - 1.f));
      *(float4*)&yp[12] = make_float4(s7h * z * (5.f * z2 - 3.f), s21_8 * x * (5.f * z2 - 1.f),
                                      s105h * z * (x2 - y2), s35_8 * x * (x2 - 3.f * y2));
    }
  }

  // sedge[p][32] = scal[snd[e_p]][:] ; two lanes per position (R4 layout)
  {
    const int p2 = base + (lane >> 1);
    const int e2 = elist[p2];
    const int sn2 = snd[e2];
    const int co = (lane & 1) * 16;
    const float* sp = scal + (size_t)sn2 * 32 + co;
    float* dp = sedge + (size_t)p2 * 32 + co;
    *(float4*)&dp[0] = *(const float4*)&sp[0];
    *(float4*)&dp[4] = *(const float4*)&sp[4];
    *(float4*)&dp[8] = *(const float4*)&sp[8];
    *(float4*)&dp[12] = *(const float4*)&sp[12];
  }

  for (int t = 0; t < 32; ++t) {
    const float4 ef0 = *(const float4*)&efs[wid][t][0];
    const float4 ef1 = *(const float4*)&efs[wid][t][4];
    float a1 = ef0.x * w1c[0];
    a1 = fmaf(ef0.y, w1c[1], a1);
    a1 = fmaf(ef0.z, w1c[2], a1);
    a1 = fmaf(ef0.w, w1c[3], a1);
    a1 = fmaf(ef1.x, w1c[4], a1);
    a1 = fmaf(ef1.y, w1c[5], a1);
    a1 = fmaf(ef1.z, w1c[6], a1);
    a1 = fmaf(ef1.w, w1c[7], a1);
    hbs[wid][lane] = silu_f(a1);
    float p0 = 0.f, p1 = 0.f, p2 = 0.f, p3 = 0.f;
#pragma unroll
    for (int k4 = 0; k4 < 16; ++k4) {
      const float4 hb = *(const float4*)&hbs[wid][k4 * 4];
      p0 = fmaf(hb.x, w2c[k4 * 4 + 0], p0);
      p1 = fmaf(hb.y, w2c[k4 * 4 + 1], p1);
      p2 = fmaf(hb.z, w2c[k4 * 4 + 2], p2);
      p3 = fmaf(hb.w, w2c[k4 * 4 + 3], p3);
    }
    hbs[wid][lane] = silu_f((p0 + p1) + (p2 + p3));
    p0 = p1 = p2 = p3 = 0.f;
#pragma unroll
    for (int k4 = 0; k4 < 16; ++k4) {
      const float4 hb = *(const float4*)&hbs[wid][k4 * 4];
      p0 = fmaf(hb.x, w3c[k4 * 4 + 0], p0);
      p1 = fmaf(hb.y, w3c[k4 * 4 + 1], p1);
      p2 = fmaf(hb.z, w3c[k4 * 4 + 2], p2);
      p3 = fmaf(hb.w, w3c[k4 * 4 + 3], p3);
    }
    const float hv = silu_f((p0 + p1) + (p2 + p3));
    const unsigned hb16 = __float_as_uint(hv) & 0xFFFF0000u;
    const float lof = hv - __uint_as_float(hb16);
    h3[(size_t)(base + t) * 128 + lane] = (unsigned short)(hb16 >> 16);
    h3[(size_t)(base + t) * 128 + 64 + lane] = (unsigned short)(__float_as_uint(lof) >> 16);
  }
}

// ---------------- node-gathered W4 GEMM via MFMA, full-K waves ------------
// Wave owns 64 columns (4 tiles) x full K=64 (hi/lo B frags in unified
// VGPR/AGPR file). Block = 4 waves = 256 cols; two col-half blocks per
// 16-node set, XCD-paired (blocks b and b+8 -> same XCD, share h3 in L2).
// Epilogue once per tile (no kh duplication); xor-reduce hoisted per node.
// A-frag: row=lm, k=kk*32+grp*8+j; B-frag col=lm, same k-map (cancels).
// C/D: col=lm, row=grp*4+reg (HW-verified). sv via R4's sedge stream+shfl.
__global__ __launch_bounds__(256, 3) void k_gather(
    const unsigned short* __restrict__ h3, const float* __restrict__ W4g,
    const float* __restrict__ Yb, const float* __restrict__ sedge,
    const int* __restrict__ row_start, float* __restrict__ agg) {
  const int ch = (blockIdx.x >> 3) & 1;
  const int ng = ((blockIdx.x >> 4) << 3) | (blockIdx.x & 7);
  const int w = threadIdx.x >> 6, lane = threadIdx.x & 63;
  const int grp = lane >> 4, lm = lane & 15;

  // B fragments: 4 tiles x 2 k-frags x hi/lo. col = ch*256 + w*64 + t*16 + lm.
  bf16x8 bhi[4][2], blo[4][2];
#pragma unroll
  for (int t = 0; t < 4; ++t) {
    const int col = ch * 256 + w * 64 + t * 16 + lm;
#pragma unroll
    for (int kk = 0; kk < 2; ++kk) {
#pragma unroll
      for (int j = 0; j < 8; ++j) {
        const float wv = W4g[(kk * 32 + grp * 8 + j) * 512 + col];
        const unsigned hb = __float_as_uint(wv) & 0xFFFF0000u;
        bhi[t][kk][j] = (short)(hb >> 16);
        blo[t][kk][j] = (short)(__float_as_uint(wv - __uint_as_float(hb)) >> 16);
      }
    }
  }

  const int nBeg = ng * 16;
  for (int n = nBeg; n < nBeg + 16; ++n) {
    const int e0 = row_start[n], e1 = row_start[n + 1];
    float outv[4] = {0.f, 0.f, 0.f, 0.f};
    for (int p0 = e0; p0 < e1; p0 += 16) {
      bf16x8 ahi0 = {0, 0, 0, 0, 0, 0, 0, 0}, ahi1 = ahi0, alo0 = ahi0, alo1 = ahi0;
      const int pa = p0 + lm;
      if (pa < e1) {
        const unsigned short* hp = h3 + (size_t)pa * 128 + grp * 8;
        ahi0 = *(const bf16x8*)(hp);
        ahi1 = *(const bf16x8*)(hp + 32);
        alo0 = *(const bf16x8*)(hp + 64);
        alo1 = *(const bf16x8*)(hp + 96);
      }
      const f32x8 sv = *(const f32x8*)(sedge + (size_t)p0 * 32 + lane * 8);
      float Yv[4];
#pragma unroll
      for (int r = 0; r < 4; ++r)
        Yv[r] = Yb[(size_t)(p0 + grp * 4 + r) * 16 + lm];
#pragma unroll
      for (int t = 0; t < 4; ++t) {
        f32x4 acc = {0.f, 0.f, 0.f, 0.f};
        acc = __builtin_amdgcn_mfma_f32_16x16x32_bf16(ahi0, bhi[t][0], acc, 0, 0, 0);
        acc = __builtin_amdgcn_mfma_f32_16x16x32_bf16(ahi1, bhi[t][1], acc, 0, 0, 0);
        acc = __builtin_amdgcn_mfma_f32_16x16x32_bf16(alo0, bhi[t][0], acc, 0, 0, 0);
        acc = __builtin_amdgcn_mfma_f32_16x16x32_bf16(alo1, bhi[t][1], acc, 0, 0, 0);
        acc = __builtin_amdgcn_mfma_f32_16x16x32_bf16(ahi0, blo[t][0], acc, 0, 0, 0);
        acc = __builtin_amdgcn_mfma_f32_16x16x32_bf16(ahi1, blo[t][1], acc, 0, 0, 0);
        // s[e_row, c] with c = ch*16 + w*4 + t: element (w&1)*4+t of the
        // holder lane ((grp*4+r)<<2) | (ch*2) | (w>>1)  (R4-verified map)
        float cp = 0.f;
#pragma unroll
        for (int r = 0; r < 4; ++r) {
          const float srt = __shfl(sv[(w & 1) * 4 + t], ((grp * 4 + r) << 2) | (ch * 2) | (w >> 1));
          cp = fmaf(acc[r] * Yv[r], srt, cp);
        }
        outv[t] += cp;
      }
    }
    const float inv12 = 1.0f / 12.0f;
#pragma unroll
    for (int t = 0; t < 4; ++t) {
      outv[t] += __shfl_xor(outv[t], 16);
      outv[t] += __shfl_xor(outv[t], 32);
      if (grp == t)
        agg[(size_t)n * 512 + ch * 256 + w * 64 + t * 16 + lm] = outv[t] * inv12;
    }
  }
}

// ---------------- per-node: Wlin, quadratic, Wprod + skip, desc out -------
__global__ __launch_bounds__(256) void k_node(
    const float* __restrict__ agg, float* __restrict__ nf,
    const float* __restrict__ Wlin, const float* __restrict__ Wprod,
    const float* __restrict__ Wskip, const float* __restrict__ w2v,
    const float* __restrict__ w3v, const int* __restrict__ elem,
    float* __restrict__ scal_out, float* __restrict__ dout, const int layer) {
  __shared__ __align__(16) float aggs[8][512];
  __shared__ __align__(16) float nfs[8][512];
  __shared__ float bs[8][544];  // pitch 17 per channel row
  const int tid = threadIdx.x;
  const int n0 = blockIdx.x * 8;
  for (int i = tid; i < 1024; i += 256) {
    const int nl = i >> 7, qq = i & 127;
    ((f32x4*)aggs)[i] = ((const f32x4*)agg)[(size_t)(n0 + nl) * 128 + qq];
    ((f32x4*)nfs)[i] = ((const f32x4*)nf)[(size_t)(n0 + nl) * 128 + qq];
  }
  __syncthreads();
  const int nl = tid >> 5, o = tid & 31;
  const int n = n0 + nl;
  constexpr int SLa[4] = {0, 1, 4, 9};
  constexpr int ELa[4] = {1, 4, 9, 16};
  float a[16];
#pragma unroll
  for (int m = 0; m < 16; ++m) a[m] = 0.f;
#pragma unroll
  for (int l = 0; l < 4; ++l) {
    for (int c = 0; c < 32; ++c) {
      const float w = Wlin[(l * 32 + c) * 32 + o];
#pragma unroll
      for (int m = SLa[l]; m < ELa[l]; ++m) a[m] = fmaf(aggs[nl][c * 16 + m], w, a[m]);
    }
  }
  const float inv = a[0];
  float p2 = 0.f;
#pragma unroll
  for (int m = 0; m < 16; ++m) p2 = fmaf(a[m], a[m], p2);
  a[0] = inv + w2v[o] * p2 + w3v[o] * inv * p2;
#pragma unroll
  for (int m = 0; m < 16; ++m) bs[nl][o * 17 + m] = a[m];
  __syncthreads();
  float outv[16];
#pragma unroll
  for (int m = 0; m < 16; ++m) outv[m] = 0.f;
#pragma unroll
  for (int l = 0; l < 4; ++l) {
    for (int c = 0; c < 32; ++c) {
      const float w = Wprod[(l * 32 + c) * 32 + o];
#pragma unroll
      for (int m = SLa[l]; m < ELa[l]; ++m) outv[m] = fmaf(bs[nl][c * 17 + m], w, outv[m]);
    }
  }
  const int z = elem[n];
  const float* wsk = Wskip + z * 1024;
  for (int c = 0; c < 32; ++c) {
    const float w = wsk[c * 32 + o];
#pragma unroll
    for (int m = 0; m < 16; ++m) outv[m] = fmaf(nfs[nl][c * 16 + m], w, outv[m]);
  }
  float* op = nf + (size_t)n * 512 + o * 16;
  *(float4*)&op[0] = make_float4(outv[0], outv[1], outv[2], outv[3]);
  *(float4*)&op[4] = make_float4(outv[4], outv[5], outv[6], outv[7]);
  *(float4*)&op[8] = make_float4(outv[8], outv[9], outv[10], outv[11]);
  *(float4*)&op[12] = make_float4(outv[12], outv[13], outv[14], outv[15]);
  scal_out[n * 32 + o] = outv[0];
  dout[(size_t)n * 64 + layer * 32 + o] = outv[0];
}

extern "C" void kernel_launch(void* const* d_in, const int* in_sizes, int n_in,
                              void* d_out, int out_size, void* d_ws, size_t ws_size,
                              hipStream_t stream) {
  const float* pos = (const float*)d_in[0];
  const float* attrs = (const float*)d_in[1];
  const float* shifts = (const float*)d_in[2];
  const int* eidx = (const int*)d_in[3];
  const float* W_embed = (const float*)d_in[4];
  const float* W1 = (const float*)d_in[5];
  const float* W2 = (const float*)d_in[6];
  const float* W3 = (const float*)d_in[7];
  const float* W4 = (const float*)d_in[8];
  const float* Wlin = (const float*)d_in[9];
  const float* Wskip = (const float*)d_in[10];
  const float* w2v = (const float*)d_in[11];
  const float* w3v = (const float*)d_in[12];
  const float* Wprod = (const float*)d_in[13];
  float* out = (float*)d_out;
  const int* snd = eidx;
  const int* rcv = eidx + N_EDGES_C;

  char* p = (char*)d_ws;
  auto take = [&](size_t bytes) {
    char* q = p;
    p += (bytes + 255) & ~(size_t)255;
    return q;
  };
  int* counts = (int*)take((size_t)N_NODES_C * 4);
  int* row_start = (int*)take((size_t)(N_NODES_C + 1) * 4);
  int* cursor = (int*)take((size_t)N_NODES_C * 4);
  int* elist = (int*)take((size_t)N_EDGES_C * 4);
  int* elem = (int*)take((size_t)N_NODES_C * 4);
  float* Ybuf = (float*)take((size_t)(N_EDGES_C + 16) * 16 * 4);
  unsigned short* h3 = (unsigned short*)take((size_t)(N_EDGES_C + 16) * 128 * 2);
  float* sedge = (float*)take((size_t)(N_EDGES_C + 16) * 32 * 4);
  float* agg = (float*)take((size_t)N_NODES_C * 512 * 4);
  float* nf = (float*)take((size_t)N_NODES_C * 512 * 4);
  float* scal0 = (float*)take((size_t)N_NODES_C * 32 * 4);
  float* scal1 = (float*)take((size_t)N_NODES_C * 32 * 4);
  (void)ws_size; (void)in_sizes; (void)n_in; (void)out_size;

  hipMemsetAsync(counts, 0, (size_t)N_NODES_C * 4, stream);
  k_count<<<N_EDGES_C / 256, 256, 0, stream>>>(rcv, counts);
  k_scan<<<1, 1024, 0, stream>>>(counts, row_start, cursor);
  k_fill<<<N_EDGES_C / 256, 256, 0, stream>>>(rcv, cursor, elist);
  k_elem<<<N_NODES_C / 256, 256, 0, stream>>>(attrs, elem);
  k_embed<<<N_NODES_C * 32 / 256, 256, 0, stream>>>(attrs, W_embed, scal0, nf);

  for (int i = 0; i < 2; ++i) {
    k_radial<<<1536, 256, 0, stream>>>(pos, shifts, snd, rcv, elist,
                                       i == 0 ? scal0 : scal1,
                                       W1 + (size_t)i * 8 * 64, W2 + (size_t)i * 64 * 64,
                                       W3 + (size_t)i * 64 * 64, h3, sedge, Ybuf,
                                       i == 0 ? 1 : 0);
    k_gather<<<2048, 256, 0, stream>>>(h3, W4 + (size_t)i * 64 * 512, Ybuf, sedge,
                                       row_start, agg);
    k_node<<<N_NODES_C / 8, 256, 0, stream>>>(agg, nf, Wlin + (size_t)i * 4096,
                                              Wprod + (size_t)i * 4096,
                                              Wskip + (size_t)i * 8192,
                                              w2v + (size_t)i * 32, w3v + (size_t)i * 32,
                                              elem, scal1, out, i);
  }
}